// Round 1
// baseline (161.534 us; speedup 1.0000x reference)
//
#include <hip/hip_runtime.h>
#include <hip/hip_bf16.h>

// INT4 group-quantized GEMV-batch (M=64, K=8192, N=28672, GS=128).
// Strategy: stream qweight (int32-per-byte, 470 MB) once; dequant to bf16 in
// registers; exchange through LDS in MFMA-fragment-shaped 16B cells; bf16 MFMA.

typedef float  f32x4 __attribute__((ext_vector_type(4)));
typedef short  s16x8 __attribute__((ext_vector_type(8)));
typedef int    i32x2 __attribute__((ext_vector_type(2)));

#define M_DIM 64
#define K_DIM 8192
#define N_DIM 28672
#define BN    64            // output cols per block
#define CK    64            // k per chunk
#define QR    32            // qweight rows per chunk (= CK/2)
#define NCHUNK (K_DIM / CK) // 128

static __device__ __forceinline__ short f2bf(float f) {
    // round-to-nearest-even f32 -> bf16
    return (short)__builtin_bit_cast(unsigned short, __float2bfloat16(f));
}

__global__ __launch_bounds__(256, 2)
void int4gemm_kernel(const float* __restrict__ x,
                     const int*   __restrict__ qw,
                     const float* __restrict__ sc,
                     const int*   __restrict__ qz,
                     const float* __restrict__ bias,
                     float*       __restrict__ out)
{
    // LDS: 16B cells [k8 0..7][idx 0..63], 8 k-contiguous bf16 each
    __shared__ s16x8 lB[8 * 64];   // B tile: idx = col within block
    __shared__ s16x8 lA[8 * 64];   // A tile: idx = batch row

    const int tid   = threadIdx.x;
    const int lane  = tid & 63;
    const int wave  = tid >> 6;
    const int nbase = blockIdx.x * BN;

    // ---- B staging coords: thread owns col-pair (2p,2p+1) x 4 qweight rows (quad q)
    const int p  = tid & 31;
    const int q  = tid >> 5;            // k8 cell index 0..7
    const int j0 = nbase + 2 * p;       // global output col (even)

    // ---- A staging coords: thread owns row am, 16 consecutive k
    const int am  = tid >> 2;           // 0..63
    const int akq = tid & 3;            // which 16-float slice of the 64-k chunk

    // ---- MFMA coords
    const int l15 = lane & 15;
    const int lk  = lane >> 4;
    const int wn  = wave * 16;          // n-tile base within block

    f32x4 acc[4];
#pragma unroll
    for (int mt = 0; mt < 4; ++mt) acc[mt] = (f32x4)0.0f;

    // current group scale/offset for this thread's two columns (group 0 first)
    float s0 = sc[j0],  s1 = sc[j0 + 1];
    float o0 = -(float)qz[j0] * s0;
    float o1 = -(float)qz[j0 + 1] * s1;
    float s0n = 0.f, s1n = 0.f;
    int   z0n = 0,   z1n = 0;

    // ---- prologue: prefetch chunk 0
    i32x2 v[4];
    f32x4 a4[4];
#pragma unroll
    for (int r = 0; r < 4; ++r)
        v[r] = *(const i32x2*)(qw + (size_t)(q * 4 + r) * N_DIM + j0);
#pragma unroll
    for (int u = 0; u < 4; ++u)
        a4[u] = *(const f32x4*)(x + (size_t)am * K_DIM + akq * 16 + u * 4);

    for (int c = 0; c < NCHUNK; ++c) {
        const int cn = c + 1;
        i32x2 v2[4];
        f32x4 a2[4];
        if (cn < NCHUNK) {
            // issue next-chunk loads early; they stay in flight across barriers
#pragma unroll
            for (int r = 0; r < 4; ++r)
                v2[r] = *(const i32x2*)(qw + (size_t)(cn * QR + q * 4 + r) * N_DIM + j0);
#pragma unroll
            for (int u = 0; u < 4; ++u)
                a2[u] = *(const f32x4*)(x + (size_t)am * K_DIM + cn * CK + akq * 16 + u * 4);
            if ((cn & 1) == 0) {  // next chunk starts a new group: prefetch s/z
                const int g = cn >> 1;
                s0n = sc[(size_t)g * N_DIM + j0];
                s1n = sc[(size_t)g * N_DIM + j0 + 1];
                z0n = qz[(size_t)g * N_DIM + j0];
                z1n = qz[(size_t)g * N_DIM + j0 + 1];
            }
        }

        // ---- dequant current qweight quad -> two bf16 cells (cols j0, j0+1)
        s16x8 c0, c1;
#pragma unroll
        for (int r = 0; r < 4; ++r) {
            const int vx = v[r].x, vy = v[r].y;
            // k = 2*i (low nibble), 2*i+1 (high nibble)
            c0[2 * r]     = f2bf(fmaf((float)(vx & 15),        s0, o0));
            c0[2 * r + 1] = f2bf(fmaf((float)((vx >> 4) & 15), s0, o0));
            c1[2 * r]     = f2bf(fmaf((float)(vy & 15),        s1, o1));
            c1[2 * r + 1] = f2bf(fmaf((float)((vy >> 4) & 15), s1, o1));
        }

        // ---- convert current x slice -> two bf16 cells (row am)
        s16x8 a0c, a1c;
#pragma unroll
        for (int u = 0; u < 2; ++u)
#pragma unroll
            for (int w = 0; w < 4; ++w)
                a0c[u * 4 + w] = f2bf(a4[u][w]);
#pragma unroll
        for (int u = 0; u < 2; ++u)
#pragma unroll
            for (int w = 0; w < 4; ++w)
                a1c[u * 4 + w] = f2bf(a4[2 + u][w]);

        __syncthreads();   // previous MFMA phase done reading LDS

        lB[q * 64 + 2 * p]         = c0;
        lB[q * 64 + 2 * p + 1]     = c1;
        lA[(akq * 2) * 64 + am]    = a0c;
        lA[(akq * 2 + 1) * 64 + am] = a1c;

        __syncthreads();   // tile ready

        // ---- MFMA: wave owns n-tile wn, all 4 m-tiles
#pragma unroll
        for (int ks = 0; ks < 2; ++ks) {
            const s16x8 bf = lB[(ks * 4 + lk) * 64 + wn + l15];
#pragma unroll
            for (int mt = 0; mt < 4; ++mt) {
                const s16x8 af = lA[(ks * 4 + lk) * 64 + mt * 16 + l15];
                acc[mt] = __builtin_amdgcn_mfma_f32_16x16x32_bf16(af, bf, acc[mt], 0, 0, 0);
            }
        }

        // ---- rotate prefetch registers
        if (cn < NCHUNK) {
#pragma unroll
            for (int r = 0; r < 4; ++r) v[r] = v2[r];
#pragma unroll
            for (int u = 0; u < 4; ++u) a4[u] = a2[u];
            if ((cn & 1) == 0) {
                s0 = s0n; s1 = s1n;
                o0 = -(float)z0n * s0n;
                o1 = -(float)z1n * s1n;
            }
        }
    }

    // ---- epilogue: bias + store (C layout: col = lane&15, row = (lane>>4)*4 + j)
    const float bv = bias[nbase + wn + l15];
#pragma unroll
    for (int mt = 0; mt < 4; ++mt) {
#pragma unroll
        for (int jj = 0; jj < 4; ++jj) {
            const int m = mt * 16 + lk * 4 + jj;
            out[(size_t)m * N_DIM + nbase + wn + l15] = acc[mt][jj] + bv;
        }
    }
}

extern "C" void kernel_launch(void* const* d_in, const int* in_sizes, int n_in,
                              void* d_out, int out_size, void* d_ws, size_t ws_size,
                              hipStream_t stream) {
    const float* x    = (const float*)d_in[0];
    const int*   qw   = (const int*)d_in[1];
    const float* sc   = (const float*)d_in[2];
    const int*   qz   = (const int*)d_in[3];
    const float* bias = (const float*)d_in[4];
    float*       out  = (float*)d_out;

    int4gemm_kernel<<<dim3(N_DIM / BN), dim3(256), 0, stream>>>(x, qw, sc, qz, bias, out);
}

// Round 2
// 122.094 us; speedup vs baseline: 1.3230x; 1.3230x over previous
//
#include <hip/hip_runtime.h>
#include <hip/hip_bf16.h>

// INT4 group-quantized decode GEMM (M=64, K=8192, N=28672, GS=128).
// y = x @ dequant(qweight) + bias.
// Round 2: pre-pass converts x -> bf16 MFMA cells (device global buffer);
// main kernel: 512 thr/block, CK=128 (=group), raw s_barrier + lgkmcnt-only
// waits (no vmcnt drain), 2-deep qweight register prefetch, bf16 MFMA.

typedef float  f32x4 __attribute__((ext_vector_type(4)));
typedef float  f32x2 __attribute__((ext_vector_type(2)));
typedef short  s16x8 __attribute__((ext_vector_type(8)));
typedef int    i32x2 __attribute__((ext_vector_type(2)));
typedef int    i32x4 __attribute__((ext_vector_type(4)));

#define M_DIM 64
#define K_DIM 8192
#define N_DIM 28672
#define BN    64             // output cols per block
#define CK    128            // k per chunk == group_size
#define NCHUNK (K_DIM / CK)  // 64

// A in bf16 cell layout: cell (c, k8, m) = 8 k-contiguous bf16 of row m,
// k = c*128 + k8*8 .. +7. Index: c*1024 + k8*64 + m.  64 chunks x 1024 cells.
__device__ s16x8 g_wsa[NCHUNK * 1024];

static __device__ __forceinline__ short f2bf(float f) {
    return (short)__builtin_bit_cast(unsigned short, __float2bfloat16(f));
}

__global__ __launch_bounds__(256)
void prep_a_kernel(const float* __restrict__ x) {
    const int tid = threadIdx.x;
    const int c   = blockIdx.x >> 2;        // 0..63
    const int mb  = blockIdx.x & 3;
    const int k8  = tid & 15;
    const int m   = mb * 16 + (tid >> 4);
    const float* src = x + (size_t)m * K_DIM + c * CK + k8 * 8;
    f32x4 a = *(const f32x4*)src;
    f32x4 b = *(const f32x4*)(src + 4);
    s16x8 o;
    o[0] = f2bf(a[0]); o[1] = f2bf(a[1]); o[2] = f2bf(a[2]); o[3] = f2bf(a[3]);
    o[4] = f2bf(b[0]); o[5] = f2bf(b[1]); o[6] = f2bf(b[2]); o[7] = f2bf(b[3]);
    g_wsa[(size_t)c * 1024 + k8 * 64 + m] = o;
}

__global__ __launch_bounds__(512, 4)
void int4gemm_kernel(const int*   __restrict__ qw,
                     const float* __restrict__ sc,
                     const int*   __restrict__ qz,
                     const float* __restrict__ bias,
                     float*       __restrict__ out)
{
    // 16B cells: [k8 0..15][idx 0..63]
    __shared__ s16x8 lB[16 * 64];   // idx = col within block
    __shared__ s16x8 lA[16 * 64];   // idx = batch row m

    const int tid   = threadIdx.x;
    const int lane  = tid & 63;
    const int wave  = tid >> 6;      // 0..7
    const int nbase = blockIdx.x * BN;

    // B staging: thread owns cols (2p, 2p+1) x byte-rows q*4..q*4+3 (cell k8=q)
    const int p  = tid & 31;
    const int q  = tid >> 5;         // 0..15
    const int j0 = nbase + 2 * p;

    // MFMA coords: 8 waves = 2 (m-half) x 4 (n-tile)
    const int l15 = lane & 15;
    const int lk  = lane >> 4;       // 0..3
    const int mh  = wave >> 2;       // 0..1
    const int wn  = (wave & 3) * 16; // n-tile base

    f32x4 acc0 = (f32x4)0.0f, acc1 = (f32x4)0.0f;

    const int* qbase = qw + j0;
    const i32x4* wsa4 = (const i32x4*)g_wsa;

    // ---- pipeline registers ----
    i32x2 bvA[4], bvB[4], bvN[4];    // qweight: cur / +1 / +2
    i32x4 av0, av1;                  // A cells for next chunk to stage
    f32x2 sA, sB, sN;
    i32x2 zA, zB, zN;

    // prologue: B chunks 0,1; scales groups 0,1; A chunk 0
#pragma unroll
    for (int r = 0; r < 4; ++r) {
        bvA[r] = *(const i32x2*)(qbase + (size_t)(q * 4 + r) * N_DIM);
        bvB[r] = *(const i32x2*)(qbase + (size_t)(64 + q * 4 + r) * N_DIM);
    }
    sA = *(const f32x2*)(sc + j0);
    sB = *(const f32x2*)(sc + N_DIM + j0);
    zA = *(const i32x2*)(qz + j0);
    zB = *(const i32x2*)(qz + N_DIM + j0);
    av0 = wsa4[tid];
    av1 = wsa4[512 + tid];

    for (int c = 0; c < NCHUNK; ++c) {
        // ---- dequant current qweight quad (uses regs loaded 2 iters ago) ----
        const float s0 = sA.x, s1 = sA.y;
        const float o0 = -(float)zA.x * s0;
        const float o1 = -(float)zA.y * s1;
        s16x8 c0, c1;
#pragma unroll
        for (int r = 0; r < 4; ++r) {
            const int vx = bvA[r].x, vy = bvA[r].y;
            c0[2 * r]     = f2bf(fmaf((float)(vx & 15),        s0, o0));
            c0[2 * r + 1] = f2bf(fmaf((float)((vx >> 4) & 15), s0, o0));
            c1[2 * r]     = f2bf(fmaf((float)(vy & 15),        s1, o1));
            c1[2 * r + 1] = f2bf(fmaf((float)((vy >> 4) & 15), s1, o1));
        }

        // barrier1: previous MFMA phase done reading LDS (no vmem drain!)
        asm volatile("s_barrier" ::: "memory");

        // stage this chunk's tiles
        lB[q * 64 + 2 * p]     = c0;
        lB[q * 64 + 2 * p + 1] = c1;
        lA[tid]       = __builtin_bit_cast(s16x8, av0);
        lA[512 + tid] = __builtin_bit_cast(s16x8, av1);

        // prefetch: A for c+1, B + scales for c+2 (wrapped; tail loads unused)
        const int ca = (c + 1) & (NCHUNK - 1);
        av0 = wsa4[(size_t)ca * 1024 + tid];
        av1 = wsa4[(size_t)ca * 1024 + 512 + tid];
        const int cb = (c + 2) & (NCHUNK - 1);
#pragma unroll
        for (int r = 0; r < 4; ++r)
            bvN[r] = *(const i32x2*)(qbase + (size_t)(cb * 64 + q * 4 + r) * N_DIM);
        sN = *(const f32x2*)(sc + (size_t)cb * N_DIM + j0);
        zN = *(const i32x2*)(qz + (size_t)cb * N_DIM + j0);

        // barrier2: LDS writes visible; vmem prefetches stay in flight
        asm volatile("s_waitcnt lgkmcnt(0)" ::: "memory");
        asm volatile("s_barrier" ::: "memory");
        __builtin_amdgcn_sched_barrier(0);

        // ---- MFMA: wave does 2 m-tiles x 1 n-tile x 4 k-slices ----
#pragma unroll
        for (int ks = 0; ks < 4; ++ks) {
            const int cell = (ks * 4 + lk) * 64;
            const s16x8 bfr = lB[cell + wn + l15];
            const s16x8 af0 = lA[cell + mh * 32 + l15];
            const s16x8 af1 = lA[cell + mh * 32 + 16 + l15];
            acc0 = __builtin_amdgcn_mfma_f32_16x16x32_bf16(af0, bfr, acc0, 0, 0, 0);
            acc1 = __builtin_amdgcn_mfma_f32_16x16x32_bf16(af1, bfr, acc1, 0, 0, 0);
        }

        // rotate pipeline
#pragma unroll
        for (int r = 0; r < 4; ++r) { bvA[r] = bvB[r]; bvB[r] = bvN[r]; }
        sA = sB; sB = sN; zA = zB; zB = zN;
    }

    // ---- epilogue: bias + store ----
    const int   ncol = nbase + wn + l15;
    const float bv   = bias[ncol];
    const int   m0   = mh * 32 + lk * 4;
#pragma unroll
    for (int jj = 0; jj < 4; ++jj) {
        out[(size_t)(m0 + jj) * N_DIM + ncol]      = acc0[jj] + bv;
        out[(size_t)(m0 + 16 + jj) * N_DIM + ncol] = acc1[jj] + bv;
    }
}

extern "C" void kernel_launch(void* const* d_in, const int* in_sizes, int n_in,
                              void* d_out, int out_size, void* d_ws, size_t ws_size,
                              hipStream_t stream) {
    const float* x    = (const float*)d_in[0];
    const int*   qw   = (const int*)d_in[1];
    const float* sc   = (const float*)d_in[2];
    const int*   qz   = (const int*)d_in[3];
    const float* bias = (const float*)d_in[4];
    float*       out  = (float*)d_out;

    prep_a_kernel<<<dim3(256), dim3(256), 0, stream>>>(x);
    int4gemm_kernel<<<dim3(N_DIM / BN), dim3(512), 0, stream>>>(qw, sc, qz, bias, out);
}